// Round 7
// baseline (54.548 us; speedup 1.0000x reference)
//
#include <hip/hip_runtime.h>

// Sliding-window attention, window=127 (+-63), B=4 L=4096 NH=16 H=64, fp32 in/out.
// Round-7: R6 structure frozen (49.9us: 512 thr, key-split wave pairs, monolithic stage).
//  - FROZEN RULE (R3+R5): no register prefetch across MFMA, no sched_barrier pinning.
//  - Staging with wide writes: K/Q f16x8 (8 thr/row), V f16x4 (4-row groups):
//    DS writes 28 -> 14 per thread, address math ~halved. All <=2-way conflicts.
//  - swap_halves via v_permlane32_swap_b32 (1 inst, both outputs) instead of
//    2 ds_bpermute + 2 cndmask.
//  - s_setprio(1) around MFMA+softmax cluster (T5: blocks desynced -> applicable regime).

typedef _Float16 f16;
typedef _Float16 f16x4  __attribute__((ext_vector_type(4)));
typedef _Float16 f16x8  __attribute__((ext_vector_type(8)));
typedef float    f32x16 __attribute__((ext_vector_type(16)));
typedef _Float16 f16x2  __attribute__((ext_vector_type(2)));
typedef int      int4v  __attribute__((ext_vector_type(4)));

constexpr int NB = 4, L = 4096, NH = 16, H = 64;
constexpr int CQ = 128, NC = L / CQ, KW = 256, WR = 63;
constexpr int RS = NH * H;   // seq-row stride in floats

constexpr int Q_OFF = 0;         // [128][64] f16, 128B rows, swizzled (16 KB)
constexpr int K_OFF = 16384;     // [256][64] f16, 128B rows, swizzled (32 KB)
constexpr int V_OFF = 49152;     // [64][256] f16 transposed, 512B rows, swizzled (32 KB)
constexpr int LDS_BYTES = 81920; // 80 KiB -> exactly 2 blocks/CU

#define DEV static __device__ __forceinline__

DEV int iclamp(int x, int lo, int hi) { return x < lo ? lo : (x > hi ? hi : x); }

DEV float fexp2(float x) {
#if __has_builtin(__builtin_amdgcn_exp2f)
    return __builtin_amdgcn_exp2f(x);
#else
    return exp2f(x);
#endif
}

DEV int packh2(float a, float b) {
    f16x2 p; p.x = (f16)a; p.y = (f16)b;   // RNE casts
    return __builtin_bit_cast(int, p);
}

// byte offset in row-major [R][64] f16 tile (128B rows), bank-conflict swizzle
DEV int rmaddr(int base, int r, int colb) {
    return base + r * 128 + (colb ^ ((r & 7) << 4));
}

// byte offset of (row h, key byte kb) in transposed V_lds (512B rows)
DEV int vaddr(int h, int kb) {
    return V_OFF + ((h * 512 + kb) ^ ((((h & 7) ^ ((h >> 3) & 7))) << 4));
}

// float index of (row q, col h) in swizzled O_lds
DEV int oaddr(int row, int col) {
    return (row * 64 + col) ^ ((row & 3) << 2);
}

// After call: a = [a_lo | b_lo], b = [a_hi | b_hi]  (v_permlane32_swap_b32 semantics:
// swaps a's upper 32 lanes with b's lower 32 lanes). Replaces 2x ds_bpermute + 2x cndmask.
DEV void swap_halves(int& a, int& b) {
    asm volatile("v_permlane32_swap_b32 %0, %1" : "+v"(a), "+v"(b));
}

__global__ __launch_bounds__(512, 4)
void wattn_kernel(const float* __restrict__ q_, const float* __restrict__ k_,
                  const float* __restrict__ v_, float* __restrict__ o_)
{
    __shared__ alignas(16) char smem[LDS_BYTES];
    float* O_lds = (float*)smem;              // aliases Q + half of K after post-loop barrier
    float* D_lds = (float*)(smem + 32768);    // 128 partial denominators (in old K region)

    // XCD-aware swizzle: 2048 blocks, 8 XCDs, 2048%8==0 -> bijective
    const int bid = (int)blockIdx.x;
    const int wid = (bid & 7) * ((NB * NH * NC) / 8) + (bid >> 3);
    const int c = wid & (NC - 1);
    const int n = (wid >> 5) & (NH - 1);
    const int b = wid >> 9;

    const int t    = (int)threadIdx.x;
    const int lane = t & 63;
    const int w    = t >> 6;        // wave 0..7
    const int lq   = lane & 31;
    const int hi   = lane >> 5;
    const int qt   = w & 3;         // query tile 0..3
    const int half = w >> 2;        // 0: key tiles qt..qt+2, 1: qt+3..qt+4

    const int kg0 = c * CQ - WR;                       // global seq row of window key j=0
    const size_t bn = ((size_t)b * L * NH + n) * H;    // element offset of (b,0,n,0)
    const float qs = 0.125f * 1.44269504088896f;       // h^-0.5 * log2(e)

    // ---- staging (wide writes) ----
    // K/Q mapping: 8 threads per 256B row, f16x8 writes
    const int rK  = t >> 3;          // 0..63
    const int hsK = (t & 7) << 3;    // float col 0,8,..,56
    // V mapping: 16 threads per 4-key-row group, f16x4 writes
    const int gV = t >> 4;           // 0..31
    const int h4 = (t & 15) << 2;    // float col 0,4,..,60

    // Q: scaled f16, rows 0..127 (2 passes)
    #pragma unroll
    for (int p = 0; p < 2; ++p) {
        int r = rK + p * 64;
        const float* src = q_ + bn + (size_t)(c * CQ + r) * RS + hsK;
        float4 a = *(const float4*)(src);
        float4 b2 = *(const float4*)(src + 4);
        *(f16x8*)(smem + rmaddr(Q_OFF, r, hsK << 1)) =
            (f16x8){(f16)(a.x * qs),  (f16)(a.y * qs),  (f16)(a.z * qs),  (f16)(a.w * qs),
                    (f16)(b2.x * qs), (f16)(b2.y * qs), (f16)(b2.z * qs), (f16)(b2.w * qs)};
    }
    // K: rows 0..255, edge-clamped (4 passes)
    #pragma unroll
    for (int p = 0; p < 4; ++p) {
        int r  = rK + p * 64;
        int kr = iclamp(kg0 + r, 0, L - 1);
        const float* src = k_ + bn + (size_t)kr * RS + hsK;
        float4 a = *(const float4*)(src);
        float4 b2 = *(const float4*)(src + 4);
        *(f16x8*)(smem + rmaddr(K_OFF, r, hsK << 1)) =
            (f16x8){(f16)a.x,  (f16)a.y,  (f16)a.z,  (f16)a.w,
                    (f16)b2.x, (f16)b2.y, (f16)b2.z, (f16)b2.w};
    }
    // V: transposed [64h][256k], 4 key rows per thread per pass (2 passes)
    #pragma unroll
    for (int p = 0; p < 2; ++p) {
        int k0 = gV * 4 + p * 128;
        float4 x0 = *(const float4*)(v_ + bn + (size_t)iclamp(kg0 + k0 + 0, 0, L - 1) * RS + h4);
        float4 x1 = *(const float4*)(v_ + bn + (size_t)iclamp(kg0 + k0 + 1, 0, L - 1) * RS + h4);
        float4 x2 = *(const float4*)(v_ + bn + (size_t)iclamp(kg0 + k0 + 2, 0, L - 1) * RS + h4);
        float4 x3 = *(const float4*)(v_ + bn + (size_t)iclamp(kg0 + k0 + 3, 0, L - 1) * RS + h4);
        int kb = k0 * 2;
        *(f16x4*)(smem + vaddr(h4 + 0, kb)) = (f16x4){(f16)x0.x, (f16)x1.x, (f16)x2.x, (f16)x3.x};
        *(f16x4*)(smem + vaddr(h4 + 1, kb)) = (f16x4){(f16)x0.y, (f16)x1.y, (f16)x2.y, (f16)x3.y};
        *(f16x4*)(smem + vaddr(h4 + 2, kb)) = (f16x4){(f16)x0.z, (f16)x1.z, (f16)x2.z, (f16)x3.z};
        *(f16x4*)(smem + vaddr(h4 + 3, kb)) = (f16x4){(f16)x0.w, (f16)x1.w, (f16)x2.w, (f16)x3.w};
    }

    // window mask bounds: allowed local keys j with j-iq in [0,126] and kg0+j in [0,L)
    const int iq  = qt * 32 + lq;
    const int jlo = (c == 0) ? WR : 0;
    const int jhi = (KW < L - kg0) ? KW : (L - kg0);
    const int lo  = (iq > jlo) ? iq : jlo;
    const int hb  = (iq + 126 < jhi - 1) ? (iq + 126) : (jhi - 1);
    const unsigned span = (unsigned)(hb - lo);

    f32x16 o0, o1;
    #pragma unroll
    for (int r = 0; r < 16; ++r) { o0[r] = 0.f; o1[r] = 0.f; }
    float dsum = 0.f;

    __syncthreads();   // staging complete

    // ---- Q fragments from LDS (B-operand: lane holds Q[q=lq][h=16tq+8hi+j]) ----
    f16x8 qf[4];
    #pragma unroll
    for (int tq = 0; tq < 4; ++tq)
        qf[tq] = *(const f16x8*)(smem + rmaddr(Q_OFF, qt * 32 + lq, 32 * tq + 16 * hi));

    auto body = [&](int kt) {
        // K fragments (A-operand: lane holds K[k=kt*32+lq][h=16tq+8hi+j])
        f16x8 kf[4];
        #pragma unroll
        for (int tq = 0; tq < 4; ++tq)
            kf[tq] = *(const f16x8*)(smem + rmaddr(K_OFF, kt * 32 + lq, 32 * tq + 16 * hi));

        // S^T tile = K_tile(32k x 64h) . Q^T
        f32x16 s;
        #pragma unroll
        for (int r = 0; r < 16; ++r) s[r] = 0.f;
        __builtin_amdgcn_s_setprio(1);
        #pragma unroll
        for (int tq = 0; tq < 4; ++tq)
            s = __builtin_amdgcn_mfma_f32_32x32x16_f16(kf[tq], qf[tq], s, 0, 0, 0);

        // mask + exp2 + denominator (per-lane: q = lq)
        const int jb = kt * 32 + 4 * hi;
        float pe[16];
        #pragma unroll
        for (int r = 0; r < 16; ++r) {
            int j = jb + (r & 3) + ((r >> 2) << 3);      // D-row -> local key index
            float e = fexp2(s[r]);
            e = ((unsigned)(j - lo) <= span) ? e : 0.f;
            dsum += e;
            pe[r] = e;
        }
        // P fragments: pack to f16 pairs, exchange across lane halves -> A-operand
        int d0 = packh2(pe[0],  pe[1]),  d1 = packh2(pe[2],  pe[3]);
        int d2 = packh2(pe[4],  pe[5]),  d3 = packh2(pe[6],  pe[7]);
        int d4 = packh2(pe[8],  pe[9]),  d5 = packh2(pe[10], pe[11]);
        int d6 = packh2(pe[12], pe[13]), d7 = packh2(pe[14], pe[15]);
        swap_halves(d0, d2); swap_halves(d1, d3);
        swap_halves(d4, d6); swap_halves(d5, d7);
        f16x8 pa0 = __builtin_bit_cast(f16x8, (int4v){d0, d1, d2, d3});   // keys kt*32 + 0..15
        f16x8 pa1 = __builtin_bit_cast(f16x8, (int4v){d4, d5, d6, d7});   // keys kt*32 + 16..31

        // PV: O[32q][64h] += P . V (B-operand from swizzled transposed V)
        const int kb = kt * 64 + hi * 16;
        f16x8 vb00 = *(const f16x8*)(smem + vaddr(lq,      kb));
        f16x8 vb01 = *(const f16x8*)(smem + vaddr(lq,      kb + 32));
        f16x8 vb10 = *(const f16x8*)(smem + vaddr(32 + lq, kb));
        f16x8 vb11 = *(const f16x8*)(smem + vaddr(32 + lq, kb + 32));
        o0 = __builtin_amdgcn_mfma_f32_32x32x16_f16(pa0, vb00, o0, 0, 0, 0);
        o0 = __builtin_amdgcn_mfma_f32_32x32x16_f16(pa1, vb01, o0, 0, 0, 0);
        o1 = __builtin_amdgcn_mfma_f32_32x32x16_f16(pa0, vb10, o1, 0, 0, 0);
        o1 = __builtin_amdgcn_mfma_f32_32x32x16_f16(pa1, vb11, o1, 0, 0, 0);
        __builtin_amdgcn_s_setprio(0);
    };

    // key-split: low wave 3 tiles, high wave 2 tiles (union = qt..qt+4)
    const int kt0 = qt + half * 3;
    body(kt0);
    body(kt0 + 1);
    if (!half) body(kt0 + 2);

    // per-query partial denominator within this wave
    float dw = dsum + __shfl_xor(dsum, 32, 64);

    __syncthreads();   // all waves done reading Q/K/V LDS; reuse for partials

    if (half) {
        // high wave: publish unnormalized partial O and partial denom
        #pragma unroll
        for (int r = 0; r < 16; ++r) {
            int qloc = (r & 3) + ((r >> 2) << 3) + 4 * hi;
            int row  = qt * 32 + qloc;
            O_lds[oaddr(row, lq)]      = o0[r];
            O_lds[oaddr(row, 32 + lq)] = o1[r];
        }
        if (lane < 32) D_lds[qt * 32 + lq] = dw;
    }
    __syncthreads();

    if (!half) {
        // low wave: combine, normalize, write final O into same slots
        float dinv = 1.0f / (dw + D_lds[iq]);
        #pragma unroll
        for (int r = 0; r < 16; ++r) {
            int qloc = (r & 3) + ((r >> 2) << 3) + 4 * hi;
            int row  = qt * 32 + qloc;
            float rd = __shfl(dinv, qloc, 64);   // dinv of query qloc lives in lane qloc
            int a0 = oaddr(row, lq), a1 = oaddr(row, 32 + lq);
            O_lds[a0] = (o0[r] + O_lds[a0]) * rd;
            O_lds[a1] = (o1[r] + O_lds[a1]) * rd;
        }
    }
    __syncthreads();

    // coalesced float4 stores: out[b][c*128+row][n][h]  (4 iters over 512 threads)
    const size_t ob = ((size_t)b * L + (size_t)c * CQ) * RS + (size_t)n * H;
    #pragma unroll
    for (int it = 0; it < 4; ++it) {
        int flat = it * 512 + t;
        int row  = flat >> 4;
        int hh   = (flat & 15) << 2;
        float4 val = *(const float4*)(O_lds + oaddr(row, hh));
        *(float4*)(o_ + ob + (size_t)row * RS + hh) = val;
    }
}

extern "C" void kernel_launch(void* const* d_in, const int* in_sizes, int n_in,
                              void* d_out, int out_size, void* d_ws, size_t ws_size,
                              hipStream_t stream) {
    const float* q = (const float*)d_in[0];
    const float* k = (const float*)d_in[1];
    const float* v = (const float*)d_in[2];
    float* o = (float*)d_out;
    (void)in_sizes; (void)n_in; (void)out_size; (void)d_ws; (void)ws_size;
    wattn_kernel<<<dim3(NB * NH * NC), dim3(512), 0, stream>>>(q, k, v, o);
}

// Round 8
// 50.732 us; speedup vs baseline: 1.0752x; 1.0752x over previous
//
#include <hip/hip_runtime.h>

// Sliding-window attention, window=127 (+-63), B=4 L=4096 NH=16 H=64, fp32 in/out.
// Round-8: R6 base (49.9us, best) + two verified/low-risk deltas:
//  - permlane32_swap for half exchange (HW-verified in R7; 4 DS ops -> 1 VALU op).
//  - two-tile ILP interleave: QK_A,QK_B -> SM_A,SM_B -> PV_A,PV_B as independent chains
//    (latency-bound diagnosis: 2 chains/wave double the scheduler's overlap options).
//  - NO setprio (R7 suspect: starves other blocks' staging overlap).
//  - FROZEN RULE (R3+R5): no global-load prefetch across MFMA, no sched_barrier pinning.
//  - Staging identical to R6 (known-good: clean 64MB writes, 2.1M conflicts).

typedef _Float16 f16;
typedef _Float16 f16x2  __attribute__((ext_vector_type(2)));
typedef _Float16 f16x4  __attribute__((ext_vector_type(4)));
typedef _Float16 f16x8  __attribute__((ext_vector_type(8)));
typedef float    f32x16 __attribute__((ext_vector_type(16)));
typedef int      int4v  __attribute__((ext_vector_type(4)));

constexpr int NB = 4, L = 4096, NH = 16, H = 64;
constexpr int CQ = 128, NC = L / CQ, KW = 256, WR = 63;
constexpr int RS = NH * H;   // seq-row stride in floats

constexpr int Q_OFF = 0;         // [128][64] f16, 128B rows, swizzled (16 KB)
constexpr int K_OFF = 16384;     // [256][64] f16, 128B rows, swizzled (32 KB)
constexpr int V_OFF = 49152;     // [64][256] f16 transposed, 512B rows, swizzled (32 KB)
constexpr int LDS_BYTES = 81920; // 80 KiB -> exactly 2 blocks/CU

#define DEV static __device__ __forceinline__

DEV int iclamp(int x, int lo, int hi) { return x < lo ? lo : (x > hi ? hi : x); }

DEV float fexp2(float x) {
#if __has_builtin(__builtin_amdgcn_exp2f)
    return __builtin_amdgcn_exp2f(x);
#else
    return exp2f(x);
#endif
}

DEV int packh2(float a, float b) {
    f16x2 p; p.x = (f16)a; p.y = (f16)b;   // RNE casts
    return __builtin_bit_cast(int, p);
}

// byte offset in row-major [R][64] f16 tile (128B rows), bank-conflict swizzle
DEV int rmaddr(int base, int r, int colb) {
    return base + r * 128 + (colb ^ ((r & 7) << 4));
}

// byte offset of (row h, key byte kb) in transposed V_lds (512B rows)
DEV int vaddr(int h, int kb) {
    return V_OFF + ((h * 512 + kb) ^ ((((h & 7) ^ ((h >> 3) & 7))) << 4));
}

// float index of (row q, col h) in swizzled O_lds
DEV int oaddr(int row, int col) {
    return (row * 64 + col) ^ ((row & 3) << 2);
}

// After call: a = [a_lo | b_lo], b = [a_hi | b_hi]. HW-verified in R7 (passed).
DEV void swap_halves(int& a, int& b) {
    asm volatile("v_permlane32_swap_b32 %0, %1" : "+v"(a), "+v"(b));
}

__global__ __launch_bounds__(512, 4)
void wattn_kernel(const float* __restrict__ q_, const float* __restrict__ k_,
                  const float* __restrict__ v_, float* __restrict__ o_)
{
    __shared__ alignas(16) char smem[LDS_BYTES];
    float* O_lds = (float*)smem;              // aliases Q + half of K after post-loop barrier
    float* D_lds = (float*)(smem + 32768);    // 128 partial denominators (in old K region)

    // XCD-aware swizzle: 2048 blocks, 8 XCDs, 2048%8==0 -> bijective
    const int bid = (int)blockIdx.x;
    const int wid = (bid & 7) * ((NB * NH * NC) / 8) + (bid >> 3);
    const int c = wid & (NC - 1);
    const int n = (wid >> 5) & (NH - 1);
    const int b = wid >> 9;

    const int t    = (int)threadIdx.x;
    const int lane = t & 63;
    const int w    = t >> 6;        // wave 0..7
    const int lq   = lane & 31;
    const int hi   = lane >> 5;
    const int qt   = w & 3;         // query tile 0..3
    const int half = w >> 2;        // 0: key tiles qt..qt+2, 1: qt+3..qt+4

    const int kg0 = c * CQ - WR;                       // global seq row of window key j=0
    const size_t bn = ((size_t)b * L * NH + n) * H;    // element offset of (b,0,n,0)
    const float qs = 0.125f * 1.44269504088896f;       // h^-0.5 * log2(e)

    // staging thread->element mapping: 32 threads per 256B source row region (R6 form)
    const int h4 = (t & 15) << 2;    // float col 0,4,..,60
    const int cb = h4 << 1;          // f16 byte col
    const int ru = t >> 4;           // 0..31

    // ---- Q stage (scaled f16), rows 0..127 ----
    {
        const float* qp = q_ + bn + (size_t)(c * CQ) * RS + h4;
        #pragma unroll
        for (int p = 0; p < 4; ++p) {
            int r = ru + p * 32;
            float4 x = *(const float4*)(qp + (size_t)r * RS);
            *(f16x4*)(smem + rmaddr(Q_OFF, r, cb)) =
                (f16x4){(f16)(x.x * qs), (f16)(x.y * qs), (f16)(x.z * qs), (f16)(x.w * qs)};
        }
    }
    // ---- K stage, rows 0..255 (edge-clamped; masked in softmax) ----
    #pragma unroll
    for (int p = 0; p < 8; ++p) {
        int r  = ru + p * 32;
        int kr = iclamp(kg0 + r, 0, L - 1);
        float4 x = *(const float4*)(k_ + bn + (size_t)kr * RS + h4);
        *(f16x4*)(smem + rmaddr(K_OFF, r, cb)) =
            (f16x4){(f16)x.x, (f16)x.y, (f16)x.z, (f16)x.w};
    }
    // ---- V stage transposed [64h][256k] ----
    #pragma unroll
    for (int p = 0; p < 4; ++p) {
        int r0  = ru * 2 + p * 64;
        int kr0 = iclamp(kg0 + r0,     0, L - 1);
        int kr1 = iclamp(kg0 + r0 + 1, 0, L - 1);
        float4 v0 = *(const float4*)(v_ + bn + (size_t)kr0 * RS + h4);
        float4 v1 = *(const float4*)(v_ + bn + (size_t)kr1 * RS + h4);
        int kb = r0 * 2;
        *(f16x2*)(smem + vaddr(h4 + 0, kb)) = (f16x2){(f16)v0.x, (f16)v1.x};
        *(f16x2*)(smem + vaddr(h4 + 1, kb)) = (f16x2){(f16)v0.y, (f16)v1.y};
        *(f16x2*)(smem + vaddr(h4 + 2, kb)) = (f16x2){(f16)v0.z, (f16)v1.z};
        *(f16x2*)(smem + vaddr(h4 + 3, kb)) = (f16x2){(f16)v0.w, (f16)v1.w};
    }

    // window mask bounds: allowed local keys j with j-iq in [0,126] and kg0+j in [0,L)
    const int iq  = qt * 32 + lq;
    const int jlo = (c == 0) ? WR : 0;
    const int jhi = (KW < L - kg0) ? KW : (L - kg0);
    const int lo  = (iq > jlo) ? iq : jlo;
    const int hb  = (iq + 126 < jhi - 1) ? (iq + 126) : (jhi - 1);
    const unsigned span = (unsigned)(hb - lo);

    f32x16 o0, o1;
    #pragma unroll
    for (int r = 0; r < 16; ++r) { o0[r] = 0.f; o1[r] = 0.f; }
    float dsum = 0.f;

    __syncthreads();   // staging complete

    // ---- Q fragments from LDS (B-operand: lane holds Q[q=lq][h=16tq+8hi+j]) ----
    f16x8 qf[4];
    #pragma unroll
    for (int tq = 0; tq < 4; ++tq)
        qf[tq] = *(const f16x8*)(smem + rmaddr(Q_OFF, qt * 32 + lq, 32 * tq + 16 * hi));

    // ---- phase helpers (independent chains; compiler interleaves) ----
    auto qk = [&](int kt, f32x16& s) {
        f16x8 kf[4];
        #pragma unroll
        for (int tq = 0; tq < 4; ++tq)
            kf[tq] = *(const f16x8*)(smem + rmaddr(K_OFF, kt * 32 + lq, 32 * tq + 16 * hi));
        #pragma unroll
        for (int r = 0; r < 16; ++r) s[r] = 0.f;
        #pragma unroll
        for (int tq = 0; tq < 4; ++tq)
            s = __builtin_amdgcn_mfma_f32_32x32x16_f16(kf[tq], qf[tq], s, 0, 0, 0);
    };
    auto sm = [&](int kt, const f32x16& s, f16x8& pa0, f16x8& pa1) {
        const int jb = kt * 32 + 4 * hi;
        float pe[16];
        #pragma unroll
        for (int r = 0; r < 16; ++r) {
            int j = jb + (r & 3) + ((r >> 2) << 3);      // D-row -> local key index
            float e = fexp2(s[r]);
            e = ((unsigned)(j - lo) <= span) ? e : 0.f;
            dsum += e;
            pe[r] = e;
        }
        int d0 = packh2(pe[0],  pe[1]),  d1 = packh2(pe[2],  pe[3]);
        int d2 = packh2(pe[4],  pe[5]),  d3 = packh2(pe[6],  pe[7]);
        int d4 = packh2(pe[8],  pe[9]),  d5 = packh2(pe[10], pe[11]);
        int d6 = packh2(pe[12], pe[13]), d7 = packh2(pe[14], pe[15]);
        swap_halves(d0, d2); swap_halves(d1, d3);
        swap_halves(d4, d6); swap_halves(d5, d7);
        pa0 = __builtin_bit_cast(f16x8, (int4v){d0, d1, d2, d3});   // keys kt*32 + 0..15
        pa1 = __builtin_bit_cast(f16x8, (int4v){d4, d5, d6, d7});   // keys kt*32 + 16..31
    };
    auto pv = [&](int kt, f16x8 pa0, f16x8 pa1) {
        const int kb = kt * 64 + hi * 16;
        f16x8 vb00 = *(const f16x8*)(smem + vaddr(lq,      kb));
        f16x8 vb01 = *(const f16x8*)(smem + vaddr(lq,      kb + 32));
        f16x8 vb10 = *(const f16x8*)(smem + vaddr(32 + lq, kb));
        f16x8 vb11 = *(const f16x8*)(smem + vaddr(32 + lq, kb + 32));
        o0 = __builtin_amdgcn_mfma_f32_32x32x16_f16(pa0, vb00, o0, 0, 0, 0);
        o0 = __builtin_amdgcn_mfma_f32_32x32x16_f16(pa1, vb01, o0, 0, 0, 0);
        o1 = __builtin_amdgcn_mfma_f32_32x32x16_f16(pa0, vb10, o1, 0, 0, 0);
        o1 = __builtin_amdgcn_mfma_f32_32x32x16_f16(pa1, vb11, o1, 0, 0, 0);
    };

    // key-split: low wave tiles qt..qt+2, high wave qt+3..qt+4; first two interleaved
    const int kt0 = qt + half * 3;
    {
        f32x16 sA, sB;
        qk(kt0,     sA);
        qk(kt0 + 1, sB);
        f16x8 paA0, paA1, paB0, paB1;
        sm(kt0,     sA, paA0, paA1);
        sm(kt0 + 1, sB, paB0, paB1);
        pv(kt0,     paA0, paA1);
        pv(kt0 + 1, paB0, paB1);
    }
    if (!half) {
        f32x16 sC;
        qk(kt0 + 2, sC);
        f16x8 paC0, paC1;
        sm(kt0 + 2, sC, paC0, paC1);
        pv(kt0 + 2, paC0, paC1);
    }

    // per-query partial denominator within this wave
    float dw = dsum + __shfl_xor(dsum, 32, 64);

    __syncthreads();   // all waves done reading Q/K/V LDS; reuse for partials

    if (half) {
        // high wave: publish unnormalized partial O and partial denom
        #pragma unroll
        for (int r = 0; r < 16; ++r) {
            int qloc = (r & 3) + ((r >> 2) << 3) + 4 * hi;
            int row  = qt * 32 + qloc;
            O_lds[oaddr(row, lq)]      = o0[r];
            O_lds[oaddr(row, 32 + lq)] = o1[r];
        }
        if (lane < 32) D_lds[qt * 32 + lq] = dw;
    }
    __syncthreads();

    if (!half) {
        // low wave: combine, normalize, write final O into same slots
        float dinv = 1.0f / (dw + D_lds[iq]);
        #pragma unroll
        for (int r = 0; r < 16; ++r) {
            int qloc = (r & 3) + ((r >> 2) << 3) + 4 * hi;
            int row  = qt * 32 + qloc;
            float rd = __shfl(dinv, qloc, 64);   // dinv of query qloc lives in lane qloc
            int a0 = oaddr(row, lq), a1 = oaddr(row, 32 + lq);
            O_lds[a0] = (o0[r] + O_lds[a0]) * rd;
            O_lds[a1] = (o1[r] + O_lds[a1]) * rd;
        }
    }
    __syncthreads();

    // coalesced float4 stores: out[b][c*128+row][n][h]  (4 iters over 512 threads)
    const size_t ob = ((size_t)b * L + (size_t)c * CQ) * RS + (size_t)n * H;
    #pragma unroll
    for (int it = 0; it < 4; ++it) {
        int flat = it * 512 + t;
        int row  = flat >> 4;
        int hh   = (flat & 15) << 2;
        float4 val = *(const float4*)(O_lds + oaddr(row, hh));
        *(float4*)(o_ + ob + (size_t)row * RS + hh) = val;
    }
}

extern "C" void kernel_launch(void* const* d_in, const int* in_sizes, int n_in,
                              void* d_out, int out_size, void* d_ws, size_t ws_size,
                              hipStream_t stream) {
    const float* q = (const float*)d_in[0];
    const float* k = (const float*)d_in[1];
    const float* v = (const float*)d_in[2];
    float* o = (float*)d_out;
    (void)in_sizes; (void)n_in; (void)out_size; (void)d_ws; (void)ws_size;
    wattn_kernel<<<dim3(NB * NH * NC), dim3(512), 0, stream>>>(q, k, v, o);
}

// Round 9
// 50.509 us; speedup vs baseline: 1.0800x; 1.0044x over previous
//
#include <hip/hip_runtime.h>

// Sliding-window attention, window=127 (+-63), B=4 L=4096 NH=16 H=64, fp32 in/out.
// Round-9: R6 base (49.9us best) + output-orientation flip.
//  - PV computed as O^T = mfma(V^T_frag, P_frag) (args swapped): A/B f16 fragments have
//    IDENTICAL per-lane layouts, so same vb/pa registers work; D' lane now holds
//    row q=lq with h in 4-consecutive chunks -> dinv lane-local, direct float4 stores
//    (one instr = 32 rows x 32B contiguous), no O LDS bounce, one barrier fewer.
//  - Key-split partial exchange via plain [64][128] fp32 O_lds (conflict-free rows);
//    LOW waves (3 tiles) publish, HIGH waves (2 tiles) combine+normalize+store.
//  - FROZEN RULE (R3+R5): no global-load prefetch across MFMA, no sched_barrier pinning.
//  - Staging identical to R6; permlane32_swap kept (R7 HW-verified).

typedef _Float16 f16;
typedef _Float16 f16x2  __attribute__((ext_vector_type(2)));
typedef _Float16 f16x4  __attribute__((ext_vector_type(4)));
typedef _Float16 f16x8  __attribute__((ext_vector_type(8)));
typedef float    f32x16 __attribute__((ext_vector_type(16)));
typedef int      int4v  __attribute__((ext_vector_type(4)));

constexpr int NB = 4, L = 4096, NH = 16, H = 64;
constexpr int CQ = 128, NC = L / CQ, KW = 256, WR = 63;
constexpr int RS = NH * H;   // seq-row stride in floats

constexpr int Q_OFF = 0;         // [128][64] f16, 128B rows, swizzled (16 KB)
constexpr int K_OFF = 16384;     // [256][64] f16, 128B rows, swizzled (32 KB)
constexpr int V_OFF = 49152;     // [64][256] f16 transposed, 512B rows, swizzled (32 KB)
constexpr int LDS_BYTES = 81920; // 80 KiB -> exactly 2 blocks/CU

#define DEV static __device__ __forceinline__

DEV int iclamp(int x, int lo, int hi) { return x < lo ? lo : (x > hi ? hi : x); }

DEV float fexp2(float x) {
#if __has_builtin(__builtin_amdgcn_exp2f)
    return __builtin_amdgcn_exp2f(x);
#else
    return exp2f(x);
#endif
}

DEV int packh2(float a, float b) {
    f16x2 p; p.x = (f16)a; p.y = (f16)b;   // RNE casts
    return __builtin_bit_cast(int, p);
}

// byte offset in row-major [R][64] f16 tile (128B rows), bank-conflict swizzle
DEV int rmaddr(int base, int r, int colb) {
    return base + r * 128 + (colb ^ ((r & 7) << 4));
}

// byte offset of (row h, key byte kb) in transposed V_lds (512B rows)
DEV int vaddr(int h, int kb) {
    return V_OFF + ((h * 512 + kb) ^ ((((h & 7) ^ ((h >> 3) & 7))) << 4));
}

// After call: a = [a_lo | b_lo], b = [a_hi | b_hi]. HW-verified in R7.
DEV void swap_halves(int& a, int& b) {
    asm volatile("v_permlane32_swap_b32 %0, %1" : "+v"(a), "+v"(b));
}

__global__ __launch_bounds__(512, 4)
void wattn_kernel(const float* __restrict__ q_, const float* __restrict__ k_,
                  const float* __restrict__ v_, float* __restrict__ o_)
{
    __shared__ alignas(16) char smem[LDS_BYTES];
    float* O_lds = (float*)smem;              // [64][128] fp32 partials, aliases Q+K post-b1
    float* D_lds = (float*)(smem + 32768);    // 128 partial denominators (in old K region)

    // XCD-aware swizzle: 2048 blocks, 8 XCDs, 2048%8==0 -> bijective
    const int bid = (int)blockIdx.x;
    const int wid = (bid & 7) * ((NB * NH * NC) / 8) + (bid >> 3);
    const int c = wid & (NC - 1);
    const int n = (wid >> 5) & (NH - 1);
    const int b = wid >> 9;

    const int t    = (int)threadIdx.x;
    const int lane = t & 63;
    const int w    = t >> 6;        // wave 0..7
    const int lq   = lane & 31;
    const int hi   = lane >> 5;
    const int qt   = w & 3;         // query tile 0..3
    const int half = w >> 2;        // 0: key tiles qt..qt+2, 1: qt+3..qt+4

    const int kg0 = c * CQ - WR;                       // global seq row of window key j=0
    const size_t bn = ((size_t)b * L * NH + n) * H;    // element offset of (b,0,n,0)
    const float qs = 0.125f * 1.44269504088896f;       // h^-0.5 * log2(e)

    // staging thread->element mapping: 32 threads per 256B source row region (R6 form)
    const int h4 = (t & 15) << 2;    // float col 0,4,..,60
    const int cb = h4 << 1;          // f16 byte col
    const int ru = t >> 4;           // 0..31

    // ---- Q stage (scaled f16), rows 0..127 ----
    {
        const float* qp = q_ + bn + (size_t)(c * CQ) * RS + h4;
        #pragma unroll
        for (int p = 0; p < 4; ++p) {
            int r = ru + p * 32;
            float4 x = *(const float4*)(qp + (size_t)r * RS);
            *(f16x4*)(smem + rmaddr(Q_OFF, r, cb)) =
                (f16x4){(f16)(x.x * qs), (f16)(x.y * qs), (f16)(x.z * qs), (f16)(x.w * qs)};
        }
    }
    // ---- K stage, rows 0..255 (edge-clamped; masked in softmax) ----
    #pragma unroll
    for (int p = 0; p < 8; ++p) {
        int r  = ru + p * 32;
        int kr = iclamp(kg0 + r, 0, L - 1);
        float4 x = *(const float4*)(k_ + bn + (size_t)kr * RS + h4);
        *(f16x4*)(smem + rmaddr(K_OFF, r, cb)) =
            (f16x4){(f16)x.x, (f16)x.y, (f16)x.z, (f16)x.w};
    }
    // ---- V stage transposed [64h][256k] ----
    #pragma unroll
    for (int p = 0; p < 4; ++p) {
        int r0  = ru * 2 + p * 64;
        int kr0 = iclamp(kg0 + r0,     0, L - 1);
        int kr1 = iclamp(kg0 + r0 + 1, 0, L - 1);
        float4 v0 = *(const float4*)(v_ + bn + (size_t)kr0 * RS + h4);
        float4 v1 = *(const float4*)(v_ + bn + (size_t)kr1 * RS + h4);
        int kb = r0 * 2;
        *(f16x2*)(smem + vaddr(h4 + 0, kb)) = (f16x2){(f16)v0.x, (f16)v1.x};
        *(f16x2*)(smem + vaddr(h4 + 1, kb)) = (f16x2){(f16)v0.y, (f16)v1.y};
        *(f16x2*)(smem + vaddr(h4 + 2, kb)) = (f16x2){(f16)v0.z, (f16)v1.z};
        *(f16x2*)(smem + vaddr(h4 + 3, kb)) = (f16x2){(f16)v0.w, (f16)v1.w};
    }

    // window mask bounds: allowed local keys j with j-iq in [0,126] and kg0+j in [0,L)
    const int iq  = qt * 32 + lq;
    const int jlo = (c == 0) ? WR : 0;
    const int jhi = (KW < L - kg0) ? KW : (L - kg0);
    const int lo  = (iq > jlo) ? iq : jlo;
    const int hb  = (iq + 126 < jhi - 1) ? (iq + 126) : (jhi - 1);
    const unsigned span = (unsigned)(hb - lo);

    f32x16 o0, o1;   // O^T fragments: lane holds row q=lq, h chunks (r&3)+8(r>>2)+4hi (+32 for o1)
    #pragma unroll
    for (int r = 0; r < 16; ++r) { o0[r] = 0.f; o1[r] = 0.f; }
    float dsum = 0.f;

    __syncthreads();   // staging complete

    // ---- Q fragments from LDS (B-operand: lane holds Q[q=lq][h=16tq+8hi+j]) ----
    f16x8 qf[4];
    #pragma unroll
    for (int tq = 0; tq < 4; ++tq)
        qf[tq] = *(const f16x8*)(smem + rmaddr(Q_OFF, qt * 32 + lq, 32 * tq + 16 * hi));

    auto body = [&](int kt) {
        // K fragments (A-operand: lane holds K[k=kt*32+lq][h=16tq+8hi+j])
        f16x8 kf[4];
        #pragma unroll
        for (int tq = 0; tq < 4; ++tq)
            kf[tq] = *(const f16x8*)(smem + rmaddr(K_OFF, kt * 32 + lq, 32 * tq + 16 * hi));

        // S^T tile = K_tile(32k x 64h) . Q^T
        f32x16 s;
        #pragma unroll
        for (int r = 0; r < 16; ++r) s[r] = 0.f;
        #pragma unroll
        for (int tq = 0; tq < 4; ++tq)
            s = __builtin_amdgcn_mfma_f32_32x32x16_f16(kf[tq], qf[tq], s, 0, 0, 0);

        // mask + exp2 + denominator (per-lane: q = lq)
        const int jb = kt * 32 + 4 * hi;
        float pe[16];
        #pragma unroll
        for (int r = 0; r < 16; ++r) {
            int j = jb + (r & 3) + ((r >> 2) << 3);      // D-row -> local key index
            float e = fexp2(s[r]);
            e = ((unsigned)(j - lo) <= span) ? e : 0.f;
            dsum += e;
            pe[r] = e;
        }
        // P fragments: pack to f16 pairs, exchange across lane halves
        // (layout serves as A in mfma(P,V) AND as B in mfma(V,P) -- identical per-lane form)
        int d0 = packh2(pe[0],  pe[1]),  d1 = packh2(pe[2],  pe[3]);
        int d2 = packh2(pe[4],  pe[5]),  d3 = packh2(pe[6],  pe[7]);
        int d4 = packh2(pe[8],  pe[9]),  d5 = packh2(pe[10], pe[11]);
        int d6 = packh2(pe[12], pe[13]), d7 = packh2(pe[14], pe[15]);
        swap_halves(d0, d2); swap_halves(d1, d3);
        swap_halves(d4, d6); swap_halves(d5, d7);
        f16x8 pa0 = __builtin_bit_cast(f16x8, (int4v){d0, d1, d2, d3});   // keys kt*32 + 0..15
        f16x8 pa1 = __builtin_bit_cast(f16x8, (int4v){d4, d5, d6, d7});   // keys kt*32 + 16..31

        // PV flipped: O^T[h][q] += V^T . P  (vb as A, pa as B; same registers as before)
        const int kb = kt * 64 + hi * 16;
        f16x8 vb00 = *(const f16x8*)(smem + vaddr(lq,      kb));
        f16x8 vb01 = *(const f16x8*)(smem + vaddr(lq,      kb + 32));
        f16x8 vb10 = *(const f16x8*)(smem + vaddr(32 + lq, kb));
        f16x8 vb11 = *(const f16x8*)(smem + vaddr(32 + lq, kb + 32));
        o0 = __builtin_amdgcn_mfma_f32_32x32x16_f16(vb00, pa0, o0, 0, 0, 0);
        o0 = __builtin_amdgcn_mfma_f32_32x32x16_f16(vb01, pa1, o0, 0, 0, 0);
        o1 = __builtin_amdgcn_mfma_f32_32x32x16_f16(vb10, pa0, o1, 0, 0, 0);
        o1 = __builtin_amdgcn_mfma_f32_32x32x16_f16(vb11, pa1, o1, 0, 0, 0);
    };

    // key-split: low wave tiles qt..qt+2, high wave qt+3..qt+4
    const int kt0 = qt + half * 3;
    body(kt0);
    body(kt0 + 1);
    if (!half) body(kt0 + 2);

    // per-query partial denominator (q = lq is lane-local in this orientation)
    float dw = dsum + __shfl_xor(dsum, 32, 64);

    __syncthreads();   // b1: all waves done reading Q/K/V LDS; reuse for partials

    if (!half) {
        // LOW wave (3 tiles): publish unnormalized partial O^T and partial denom.
        // O_lds[h][q]: lanes write 32 consecutive q floats per row -> conflict-free.
        #pragma unroll
        for (int r = 0; r < 16; ++r) {
            int h = (r & 3) + ((r >> 2) << 3) + 4 * hi;
            O_lds[h * 128 + iq]        = o0[r];
            O_lds[(32 + h) * 128 + iq] = o1[r];
        }
        if (lane < 32) D_lds[iq] = dw;
    }
    __syncthreads();   // b2

    if (half) {
        // HIGH wave (2 tiles): combine, normalize (dinv lane-local), direct float4 stores.
        // Store instr m: 32 rows x 32B contiguous (lo lane h=8m.., hi lane h=8m+4..).
        float dinv = 1.0f / (dw + D_lds[iq]);
        const size_t ob = ((size_t)b * L + (size_t)c * CQ) * RS + (size_t)n * H;
        float* orow = o_ + ob + (size_t)iq * RS;
        #pragma unroll
        for (int m = 0; m < 4; ++m) {
            int h0 = 8 * m + 4 * hi;
            float4 v0, v1;
            v0.x = (o0[4 * m + 0] + O_lds[(h0 + 0) * 128 + iq]) * dinv;
            v0.y = (o0[4 * m + 1] + O_lds[(h0 + 1) * 128 + iq]) * dinv;
            v0.z = (o0[4 * m + 2] + O_lds[(h0 + 2) * 128 + iq]) * dinv;
            v0.w = (o0[4 * m + 3] + O_lds[(h0 + 3) * 128 + iq]) * dinv;
            v1.x = (o1[4 * m + 0] + O_lds[(32 + h0 + 0) * 128 + iq]) * dinv;
            v1.y = (o1[4 * m + 1] + O_lds[(32 + h0 + 1) * 128 + iq]) * dinv;
            v1.z = (o1[4 * m + 2] + O_lds[(32 + h0 + 2) * 128 + iq]) * dinv;
            v1.w = (o1[4 * m + 3] + O_lds[(32 + h0 + 3) * 128 + iq]) * dinv;
            *(float4*)(orow + h0)      = v0;
            *(float4*)(orow + 32 + h0) = v1;
        }
    }
}

extern "C" void kernel_launch(void* const* d_in, const int* in_sizes, int n_in,
                              void* d_out, int out_size, void* d_ws, size_t ws_size,
                              hipStream_t stream) {
    const float* q = (const float*)d_in[0];
    const float* k = (const float*)d_in[1];
    const float* v = (const float*)d_in[2];
    float* o = (float*)d_out;
    (void)in_sizes; (void)n_in; (void)out_size; (void)d_ws; (void)ws_size;
    wattn_kernel<<<dim3(NB * NH * NC), dim3(512), 0, stream>>>(q, k, v, o);
}

// Round 10
// 49.121 us; speedup vs baseline: 1.1105x; 1.0282x over previous
//
#include <hip/hip_runtime.h>

// Sliding-window attention, window=127 (+-63), B=4 L=4096 NH=16 H=64, fp32 in/out.
// Round-10: R9 structure (O^T flip epilogue, clean 65.5MB writes) + staging MLP fix.
//  - Diagnosis: VGPR=60 under launch_bounds(512,4) -> compiler holds only ~4-6 of 20
//    staging loads in flight -> stage phase = ~4 serial latency batches. R4's
//    waves_per_eu(2,2) build reached 88 VGPRs with zero spill -> attribute controls this.
//  - Fix: load-ALL-then-write-ALL staging (20 float4 into unrolled static buffers, then
//    all cvt+ds_writes), amdgpu_waves_per_eu(2,4) for a 256-VGPR ceiling. No MFMA in
//    between -> frozen rule (R3/R5: no pinned prefetch across MFMA) not violated.
//  - Occupancy unchanged (LDS-capped 2 blocks/CU = 4 waves/EU, legal for (2,4)).
//  - Everything else identical to R9.

typedef _Float16 f16;
typedef _Float16 f16x2  __attribute__((ext_vector_type(2)));
typedef _Float16 f16x4  __attribute__((ext_vector_type(4)));
typedef _Float16 f16x8  __attribute__((ext_vector_type(8)));
typedef float    f32x16 __attribute__((ext_vector_type(16)));
typedef int      int4v  __attribute__((ext_vector_type(4)));

constexpr int NB = 4, L = 4096, NH = 16, H = 64;
constexpr int CQ = 128, NC = L / CQ, KW = 256, WR = 63;
constexpr int RS = NH * H;   // seq-row stride in floats

constexpr int Q_OFF = 0;         // [128][64] f16, 128B rows, swizzled (16 KB)
constexpr int K_OFF = 16384;     // [256][64] f16, 128B rows, swizzled (32 KB)
constexpr int V_OFF = 49152;     // [64][256] f16 transposed, 512B rows, swizzled (32 KB)
constexpr int LDS_BYTES = 81920; // 80 KiB -> exactly 2 blocks/CU

#define DEV static __device__ __forceinline__

DEV int iclamp(int x, int lo, int hi) { return x < lo ? lo : (x > hi ? hi : x); }

DEV float fexp2(float x) {
#if __has_builtin(__builtin_amdgcn_exp2f)
    return __builtin_amdgcn_exp2f(x);
#else
    return exp2f(x);
#endif
}

DEV int packh2(float a, float b) {
    f16x2 p; p.x = (f16)a; p.y = (f16)b;   // RNE casts
    return __builtin_bit_cast(int, p);
}

// byte offset in row-major [R][64] f16 tile (128B rows), bank-conflict swizzle
DEV int rmaddr(int base, int r, int colb) {
    return base + r * 128 + (colb ^ ((r & 7) << 4));
}

// byte offset of (row h, key byte kb) in transposed V_lds (512B rows)
DEV int vaddr(int h, int kb) {
    return V_OFF + ((h * 512 + kb) ^ ((((h & 7) ^ ((h >> 3) & 7))) << 4));
}

// After call: a = [a_lo | b_lo], b = [a_hi | b_hi]. HW-verified in R7.
DEV void swap_halves(int& a, int& b) {
    asm volatile("v_permlane32_swap_b32 %0, %1" : "+v"(a), "+v"(b));
}

__global__ __launch_bounds__(512) __attribute__((amdgpu_waves_per_eu(2, 4)))
void wattn_kernel(const float* __restrict__ q_, const float* __restrict__ k_,
                  const float* __restrict__ v_, float* __restrict__ o_)
{
    __shared__ alignas(16) char smem[LDS_BYTES];
    float* O_lds = (float*)smem;              // [64][128] fp32 partials, aliases Q+K post-b1
    float* D_lds = (float*)(smem + 32768);    // 128 partial denominators (in old K region)

    // XCD-aware swizzle: 2048 blocks, 8 XCDs, 2048%8==0 -> bijective
    const int bid = (int)blockIdx.x;
    const int wid = (bid & 7) * ((NB * NH * NC) / 8) + (bid >> 3);
    const int c = wid & (NC - 1);
    const int n = (wid >> 5) & (NH - 1);
    const int b = wid >> 9;

    const int t    = (int)threadIdx.x;
    const int lane = t & 63;
    const int w    = t >> 6;        // wave 0..7
    const int lq   = lane & 31;
    const int hi   = lane >> 5;
    const int qt   = w & 3;         // query tile 0..3
    const int half = w >> 2;        // 0: key tiles qt..qt+2, 1: qt+3..qt+4

    const int kg0 = c * CQ - WR;                       // global seq row of window key j=0
    const size_t bn = ((size_t)b * L * NH + n) * H;    // element offset of (b,0,n,0)
    const float qs = 0.125f * 1.44269504088896f;       // h^-0.5 * log2(e)

    // staging thread->element mapping: 32 threads per 256B source row region
    const int h4 = (t & 15) << 2;    // float col 0,4,..,60
    const int cb = h4 << 1;          // f16 byte col
    const int ru = t >> 4;           // 0..31

    // ================= staging: LOAD ALL (20 float4 in flight) =================
    float4 kb_[8], qb_[4], vb_[8];
    {
        #pragma unroll
        for (int p = 0; p < 8; ++p) {
            int kr = iclamp(kg0 + ru + p * 32, 0, L - 1);
            kb_[p] = *(const float4*)(k_ + bn + (size_t)kr * RS + h4);
        }
        const float* qp = q_ + bn + (size_t)(c * CQ) * RS + h4;
        #pragma unroll
        for (int p = 0; p < 4; ++p)
            qb_[p] = *(const float4*)(qp + (size_t)(ru + p * 32) * RS);
        #pragma unroll
        for (int p = 0; p < 4; ++p) {
            int r0  = ru * 2 + p * 64;
            vb_[2 * p]     = *(const float4*)(v_ + bn + (size_t)iclamp(kg0 + r0,     0, L - 1) * RS + h4);
            vb_[2 * p + 1] = *(const float4*)(v_ + bn + (size_t)iclamp(kg0 + r0 + 1, 0, L - 1) * RS + h4);
        }
    }
    // ================= staging: WRITE ALL (cvt + ds_write) =================
    #pragma unroll
    for (int p = 0; p < 8; ++p) {
        float4 x = kb_[p];
        *(f16x4*)(smem + rmaddr(K_OFF, ru + p * 32, cb)) =
            (f16x4){(f16)x.x, (f16)x.y, (f16)x.z, (f16)x.w};
    }
    #pragma unroll
    for (int p = 0; p < 4; ++p) {
        float4 x = qb_[p];
        *(f16x4*)(smem + rmaddr(Q_OFF, ru + p * 32, cb)) =
            (f16x4){(f16)(x.x * qs), (f16)(x.y * qs), (f16)(x.z * qs), (f16)(x.w * qs)};
    }
    #pragma unroll
    for (int p = 0; p < 4; ++p) {
        float4 v0 = vb_[2 * p], v1 = vb_[2 * p + 1];
        int kb = (ru * 2 + p * 64) * 2;
        *(f16x2*)(smem + vaddr(h4 + 0, kb)) = (f16x2){(f16)v0.x, (f16)v1.x};
        *(f16x2*)(smem + vaddr(h4 + 1, kb)) = (f16x2){(f16)v0.y, (f16)v1.y};
        *(f16x2*)(smem + vaddr(h4 + 2, kb)) = (f16x2){(f16)v0.z, (f16)v1.z};
        *(f16x2*)(smem + vaddr(h4 + 3, kb)) = (f16x2){(f16)v0.w, (f16)v1.w};
    }

    // window mask bounds: allowed local keys j with j-iq in [0,126] and kg0+j in [0,L)
    const int iq  = qt * 32 + lq;
    const int jlo = (c == 0) ? WR : 0;
    const int jhi = (KW < L - kg0) ? KW : (L - kg0);
    const int lo  = (iq > jlo) ? iq : jlo;
    const int hb  = (iq + 126 < jhi - 1) ? (iq + 126) : (jhi - 1);
    const unsigned span = (unsigned)(hb - lo);

    f32x16 o0, o1;   // O^T fragments: lane holds row q=lq, h chunks (r&3)+8(r>>2)+4hi (+32 for o1)
    #pragma unroll
    for (int r = 0; r < 16; ++r) { o0[r] = 0.f; o1[r] = 0.f; }
    float dsum = 0.f;

    __syncthreads();   // staging complete

    // ---- Q fragments from LDS (B-operand: lane holds Q[q=lq][h=16tq+8hi+j]) ----
    f16x8 qf[4];
    #pragma unroll
    for (int tq = 0; tq < 4; ++tq)
        qf[tq] = *(const f16x8*)(smem + rmaddr(Q_OFF, qt * 32 + lq, 32 * tq + 16 * hi));

    auto body = [&](int kt) {
        // K fragments (A-operand: lane holds K[k=kt*32+lq][h=16tq+8hi+j])
        f16x8 kf[4];
        #pragma unroll
        for (int tq = 0; tq < 4; ++tq)
            kf[tq] = *(const f16x8*)(smem + rmaddr(K_OFF, kt * 32 + lq, 32 * tq + 16 * hi));

        // S^T tile = K_tile(32k x 64h) . Q^T
        f32x16 s;
        #pragma unroll
        for (int r = 0; r < 16; ++r) s[r] = 0.f;
        #pragma unroll
        for (int tq = 0; tq < 4; ++tq)
            s = __builtin_amdgcn_mfma_f32_32x32x16_f16(kf[tq], qf[tq], s, 0, 0, 0);

        // mask + exp2 + denominator (per-lane: q = lq)
        const int jb = kt * 32 + 4 * hi;
        float pe[16];
        #pragma unroll
        for (int r = 0; r < 16; ++r) {
            int j = jb + (r & 3) + ((r >> 2) << 3);      // D-row -> local key index
            float e = fexp2(s[r]);
            e = ((unsigned)(j - lo) <= span) ? e : 0.f;
            dsum += e;
            pe[r] = e;
        }
        // P fragments: pack to f16 pairs, exchange across lane halves
        int d0 = packh2(pe[0],  pe[1]),  d1 = packh2(pe[2],  pe[3]);
        int d2 = packh2(pe[4],  pe[5]),  d3 = packh2(pe[6],  pe[7]);
        int d4 = packh2(pe[8],  pe[9]),  d5 = packh2(pe[10], pe[11]);
        int d6 = packh2(pe[12], pe[13]), d7 = packh2(pe[14], pe[15]);
        swap_halves(d0, d2); swap_halves(d1, d3);
        swap_halves(d4, d6); swap_halves(d5, d7);
        f16x8 pa0 = __builtin_bit_cast(f16x8, (int4v){d0, d1, d2, d3});   // keys kt*32 + 0..15
        f16x8 pa1 = __builtin_bit_cast(f16x8, (int4v){d4, d5, d6, d7});   // keys kt*32 + 16..31

        // PV flipped: O^T[h][q] += V^T . P  (vb as A, pa as B)
        const int kb = kt * 64 + hi * 16;
        f16x8 vb00 = *(const f16x8*)(smem + vaddr(lq,      kb));
        f16x8 vb01 = *(const f16x8*)(smem + vaddr(lq,      kb + 32));
        f16x8 vb10 = *(const f16x8*)(smem + vaddr(32 + lq, kb));
        f16x8 vb11 = *(const f16x8*)(smem + vaddr(32 + lq, kb + 32));
        o0 = __builtin_amdgcn_mfma_f32_32x32x16_f16(vb00, pa0, o0, 0, 0, 0);
        o0 = __builtin_amdgcn_mfma_f32_32x32x16_f16(vb01, pa1, o0, 0, 0, 0);
        o1 = __builtin_amdgcn_mfma_f32_32x32x16_f16(vb10, pa0, o1, 0, 0, 0);
        o1 = __builtin_amdgcn_mfma_f32_32x32x16_f16(vb11, pa1, o1, 0, 0, 0);
    };

    // key-split: low wave tiles qt..qt+2, high wave qt+3..qt+4
    const int kt0 = qt + half * 3;
    body(kt0);
    body(kt0 + 1);
    if (!half) body(kt0 + 2);

    // per-query partial denominator (q = lq is lane-local in this orientation)
    float dw = dsum + __shfl_xor(dsum, 32, 64);

    __syncthreads();   // b1: all waves done reading Q/K/V LDS; reuse for partials

    if (!half) {
        // LOW wave (3 tiles): publish unnormalized partial O^T and partial denom.
        #pragma unroll
        for (int r = 0; r < 16; ++r) {
            int h = (r & 3) + ((r >> 2) << 3) + 4 * hi;
            O_lds[h * 128 + iq]        = o0[r];
            O_lds[(32 + h) * 128 + iq] = o1[r];
        }
        if (lane < 32) D_lds[iq] = dw;
    }
    __syncthreads();   // b2

    if (half) {
        // HIGH wave (2 tiles): combine, normalize (dinv lane-local), direct float4 stores.
        float dinv = 1.0f / (dw + D_lds[iq]);
        const size_t ob = ((size_t)b * L + (size_t)c * CQ) * RS + (size_t)n * H;
        float* orow = o_ + ob + (size_t)iq * RS;
        #pragma unroll
        for (int m = 0; m < 4; ++m) {
            int h0 = 8 * m + 4 * hi;
            float4 v0, v1;
            v0.x = (o0[4 * m + 0] + O_lds[(h0 + 0) * 128 + iq]) * dinv;
            v0.y = (o0[4 * m + 1] + O_lds[(h0 + 1) * 128 + iq]) * dinv;
            v0.z = (o0[4 * m + 2] + O_lds[(h0 + 2) * 128 + iq]) * dinv;
            v0.w = (o0[4 * m + 3] + O_lds[(h0 + 3) * 128 + iq]) * dinv;
            v1.x = (o1[4 * m + 0] + O_lds[(32 + h0 + 0) * 128 + iq]) * dinv;
            v1.y = (o1[4 * m + 1] + O_lds[(32 + h0 + 1) * 128 + iq]) * dinv;
            v1.z = (o1[4 * m + 2] + O_lds[(32 + h0 + 2) * 128 + iq]) * dinv;
            v1.w = (o1[4 * m + 3] + O_lds[(32 + h0 + 3) * 128 + iq]) * dinv;
            *(float4*)(orow + h0)      = v0;
            *(float4*)(orow + 32 + h0) = v1;
        }
    }
}

extern "C" void kernel_launch(void* const* d_in, const int* in_sizes, int n_in,
                              void* d_out, int out_size, void* d_ws, size_t ws_size,
                              hipStream_t stream) {
    const float* q = (const float*)d_in[0];
    const float* k = (const float*)d_in[1];
    const float* v = (const float*)d_in[2];
    float* o = (float*)d_out;
    (void)in_sizes; (void)n_in; (void)out_size; (void)d_ws; (void)ws_size;
    wattn_kernel<<<dim3(NB * NH * NC), dim3(512), 0, stream>>>(q, k, v, o);
}